// Round 7
// baseline (138.212 us; speedup 1.0000x reference)
//
#include <hip/hip_runtime.h>
#include <hip/hip_bf16.h>

typedef __attribute__((ext_vector_type(8))) short short8;   // 8 bf16 (4 VGPRs)
typedef __attribute__((ext_vector_type(4))) float f32x4;    // MFMA acc

// Problem constants
static constexpr int HW = 1024;   // 32*32
static constexpr int C2 = 160;    // corr channel count
static constexpr int FS = 168;    // corr/epilogue LDS row stride in shorts (336 B)
static constexpr int WPLANE = 160 * 40;  // shorts per (ks,mat,hl) w-plane
static constexpr int WKS = 4 * WPLANE;
static constexpr int KSTEPS = 10;
static constexpr size_t PL = 32ull * 1024 * 160;   // shorts per f-plane (10.49MB)
static constexpr size_t PPL = 32ull * 256 * 160;   // shorts per pooled plane

__device__ inline short bfh(float v) {
  __hip_bfloat16 h = __float2bfloat16(v);
  return *reinterpret_cast<short*>(&h);
}
__device__ inline float bff(short s) {
  union { unsigned u; float f; } c;
  c.u = ((unsigned)(unsigned short)s) << 16;
  return c.f;
}

// ---------------------------------------------------------------------------
// Kernel 0: pre-split w into bf16 (hi,lo) planes, tiled per k-step (unchanged).
// wp[ks][mat][hl][o 160][kk 40], kk 32..39 zero.
// ---------------------------------------------------------------------------
__global__ __launch_bounds__(256)
void wprep_kernel(const float* __restrict__ w0, const float* __restrict__ w1,
                  short* __restrict__ wp) {
  const int id = blockIdx.x * 256 + threadIdx.x;
  if (id >= KSTEPS * WKS) return;
  const int kk = id % 40;
  const int o = (id / 40) % 160;
  const int hl = (id / 6400) % 2;
  const int mat = (id / 12800) % 2;
  const int ks = id / 25600;
  short outv = 0;
  if (kk < 32) {
    const float v = (mat ? w1 : w0)[o * 320 + ks * 32 + kk];
    const short hb = bfh(v);
    outv = hl ? bfh(v - bff(hb)) : hb;
  }
  wp[id] = outv;
}

// ---------------------------------------------------------------------------
// Kernel 1 (ROUND-7 REWRITE): 1x1 convs, block = (pxt 32, q 8, bb 4) = 1024
// blocks, 4 waves, M=40 (W0 rows 20q..+19 as gr 0-19, W1 same as gr 20-39,
// gr 40-47 pad), N = 9 frames x 32 px, K = 320.
//  - x staged as RAW fp32 into XOR-swizzled LDS (phys px4 = px4 ^ (kk-group*2));
//    writes are linear (conflict-free), B-frag b32 reads land 2 lanes/bank.
//  - fp32 -> split-bf16 conversion at the CONSUMER, overlapped with MFMA.
//  - A-fragments read directly from global wprep (L2-hot) - no LDS staging.
//  - LDS 36.9 KB -> 4 blocks/CU. Natural grid order: the 8 q-blocks sharing
//    an x-tile have flat stride 32 -> same XCD -> x L2-resident after first.
// Epilogue identical math to round 6, split into per-mat passes via tL
// (overlays xB). Output layout identical to round 6 (verified).
// ---------------------------------------------------------------------------
__global__ __launch_bounds__(256)
void conv_q(const float* __restrict__ x, const short* __restrict__ wprep,
            short* __restrict__ f0bh, short* __restrict__ f0bl,
            short* __restrict__ f1bh, short* __restrict__ f1bl) {
  __shared__ __align__(16) float xB[9216];   // [f 9][kk 32][px4_phys 8][4]
  const int pxt = blockIdx.x;   // 0..31
  const int q = blockIdx.y;     // 0..7
  const int bb = blockIdx.z;    // 0..3
  const int tid = threadIdx.x;
  const int lane = tid & 63;
  const int wave = __builtin_amdgcn_readfirstlane(tid >> 6);
  const int lr = lane & 15, kg = lane >> 4;
  const int pxh = wave & 1;    // px half (16)
  const int fpar = wave >> 1;  // frame parity
  const int n = bb * 8 + q;

  // A-fragment per-lane short-offsets (hl=0 plane; +WPLANE for lo)
  int aoff[3];
#pragma unroll
  for (int mt = 0; mt < 3; ++mt) {
    const int gr = mt * 16 + lr;
    const int mat = gr >= 20;
    int r = gr - mat * 20;
    if (r > 19) r = 19;  // pad rows gr 40..47: clamp (never stored)
    aoff[mt] = mat * 2 * WPLANE + (q * 20 + r) * 40 + kg * 8;
  }
  // B-read swizzled base: element (f, kk=kg*8+j, px=pxh*16+lr)
  const int pxq = ((pxh * 4 + (lr >> 2)) ^ (kg << 1)) & 7;
  const int bbase = kg * 256 + pxq * 4 + (lr & 3);

  const int l8 = lane >> 3, l7 = lane & 7;
  const float* xg = x + (size_t)bb * 320 * 9216 + (size_t)pxt * 32;

  f32x4 acc[3][5];
#pragma unroll
  for (int mt = 0; mt < 3; ++mt)
#pragma unroll
    for (int fi = 0; fi < 5; ++fi)
#pragma unroll
      for (int r = 0; r < 4; ++r) acc[mt][fi][r] = 0.f;

  for (int ks = 0; ks < KSTEPS; ++ks) {
    __syncthreads();  // previous xB readers done
    // stage 36 KB fp32: per wave 9 x (global float4 -> linear LDS write),
    // global px pre-swizzled so LDS stays linear (write side of the XOR).
#pragma unroll
    for (int g = 0; g < 2; ++g) {
      float4 xr[5];
      const int jn = g ? 4 : 5;
#pragma unroll
      for (int j = 0; j < 5; ++j) {
        if (j < jn) {
          const int gi = wave * 9 + g * 5 + j;
          const int f = gi >> 2, k4 = gi & 3;
          const int kk = k4 * 8 + l8;
          xr[j] = *reinterpret_cast<const float4*>(
              xg + (size_t)(ks * 32 + kk) * 9216 + f * 1024 +
              ((l7 ^ (k4 << 1)) << 2));
        }
      }
#pragma unroll
      for (int j = 0; j < 5; ++j) {
        if (j < jn) {
          const int gi = wave * 9 + g * 5 + j;
          *reinterpret_cast<float4*>(xB + gi * 256 + lane * 4) = xr[j];
        }
      }
    }
    __syncthreads();

    // A-frags from global (L2-hot wprep)
    short8 Ah[3], Al[3];
    const short* wks = wprep + (size_t)ks * WKS;
#pragma unroll
    for (int mt = 0; mt < 3; ++mt) {
      Ah[mt] = *reinterpret_cast<const short8*>(wks + aoff[mt]);
      Al[mt] = *reinterpret_cast<const short8*>(wks + aoff[mt] + WPLANE);
    }
#pragma unroll
    for (int fi = 0; fi < 5; ++fi) {
      const int f = 2 * fi + fpar;
      if (f < 9) {  // wave-uniform guard
        const float* xf = xB + f * 1024 + bbase;
        float xv[8];
#pragma unroll
        for (int j2 = 0; j2 < 8; ++j2) xv[j2] = xf[j2 * 32];
        short8 Bh, Bl;
#pragma unroll
        for (int j2 = 0; j2 < 8; ++j2) {
          const short h = bfh(xv[j2]);
          Bh[j2] = h;
          Bl[j2] = bfh(xv[j2] - bff(h));
        }
#pragma unroll
        for (int mt = 0; mt < 3; ++mt) {
          acc[mt][fi] = __builtin_amdgcn_mfma_f32_16x16x32_bf16(
              Ah[mt], Bh, acc[mt][fi], 0, 0, 0);
          acc[mt][fi] = __builtin_amdgcn_mfma_f32_16x16x32_bf16(
              Ah[mt], Bl, acc[mt][fi], 0, 0, 0);
          acc[mt][fi] = __builtin_amdgcn_mfma_f32_16x16x32_bf16(
              Al[mt], Bh, acc[mt][fi], 0, 0, 0);
        }
      }
    }
  }

  // ---- epilogue: two mat-passes via LDS transpose (tL overlays xB) ----
  short* tL = reinterpret_cast<short*>(xB);  // [2 planes][32 rows][168]
#pragma unroll
  for (int m = 0; m < 2; ++m) {
    __syncthreads();  // xB readers / previous copy-out done
#pragma unroll
    for (int mt = 0; mt < 3; ++mt)
#pragma unroll
      for (int fi = 0; fi < 5; ++fi) {
        const int f = 2 * fi + fpar;
        const int tt = f - m;
        if (f < 9 && (unsigned)tt < 8u) {
#pragma unroll
          for (int rr = 0; rr < 4; ++rr) {
            const int gr = mt * 16 + kg * 4 + rr;
            const bool ok = m ? (gr >= 20 && gr < 40) : (gr < 20);
            if (ok) {
              const int r20 = gr - m * 20;
              const int c = 8 * r20 + tt;
              const int row = pxh * 16 + lr;
              const float v = acc[mt][fi][rr];
              const short h = bfh(v);
              tL[row * FS + c] = h;
              tL[5376 + row * FS + c] = bfh(v - bff(h));
            }
          }
        }
      }
    __syncthreads();
    // coalesced copy-out: 1280 uint4
#pragma unroll
    for (int i = 0; i < 5; ++i) {
      const int idx = tid + i * 256;
      const int plane = idx / 640, rem = idx % 640;
      const int row = rem / 20, c16 = rem % 20;
      short* dst = m ? (plane ? f1bl : f1bh) : (plane ? f0bl : f0bh);
      *reinterpret_cast<uint4*>(
          dst + ((size_t)n * 1024 + pxt * 32 + row) * 160 + c16 * 8) =
          *reinterpret_cast<const uint4*>(&tL[plane * 5376 + row * FS + c16 * 8]);
    }
  }
}

// ---------------------------------------------------------------------------
// Kernel 2: 2x2 avg-pool on the bf16 h/l planes (unchanged from round 6)
// ---------------------------------------------------------------------------
__global__ __launch_bounds__(256)
void pool_b(const short* __restrict__ f1bh, const short* __restrict__ f1bl,
            short* __restrict__ g1pbh, short* __restrict__ g1pbl) {
  const int id = blockIdx.x * 256 + threadIdx.x;  // 32*256*20
  if (id >= 32 * 256 * 20) return;
  const int c16 = id % 20;
  const int PX = (id / 20) & 255;
  const int n = id / (20 * 256);
  const int Y = PX >> 4, X = PX & 15;
  const int r0 = Y * 64 + X * 2;
  const size_t base = ((size_t)n * 1024 + r0) * 160 + c16 * 8;
  const short8 h00 = *reinterpret_cast<const short8*>(f1bh + base);
  const short8 h01 = *reinterpret_cast<const short8*>(f1bh + base + 160);
  const short8 h10 = *reinterpret_cast<const short8*>(f1bh + base + 32 * 160);
  const short8 h11 = *reinterpret_cast<const short8*>(f1bh + base + 33 * 160);
  const short8 l00 = *reinterpret_cast<const short8*>(f1bl + base);
  const short8 l01 = *reinterpret_cast<const short8*>(f1bl + base + 160);
  const short8 l10 = *reinterpret_cast<const short8*>(f1bl + base + 32 * 160);
  const short8 l11 = *reinterpret_cast<const short8*>(f1bl + base + 33 * 160);
  short8 ho, lo;
#pragma unroll
  for (int j = 0; j < 8; ++j) {
    const float v = 0.25f * ((bff(h00[j]) + bff(l00[j])) + (bff(h01[j]) + bff(l01[j])) +
                             (bff(h10[j]) + bff(l10[j])) + (bff(h11[j]) + bff(l11[j])));
    const short h = bfh(v);
    ho[j] = h;
    lo[j] = bfh(v - bff(h));
  }
  const size_t ob = ((size_t)n * 256 + PX) * 160 + c16 * 8;
  *reinterpret_cast<short8*>(g1pbh + ob) = ho;
  *reinterpret_cast<short8*>(g1pbl + ob) = lo;
}

// ---------------------------------------------------------------------------
// Kernel 3: correlation + pyramid sampling via split-bf16 MFMA
// (unchanged from round 6 — verified; XCD swizzle kept)
// ---------------------------------------------------------------------------
__global__ __launch_bounds__(256)
void corr_kernel(const short* __restrict__ f0bh, const short* __restrict__ f0bl,
                 const short* __restrict__ f1bh, const short* __restrict__ f1bl,
                 const short* __restrict__ g1pbh, const short* __restrict__ g1pbl,
                 float* __restrict__ out) {
  __shared__ __align__(16) short f0L[2][32 * FS];
  __shared__ __align__(16) short f1L[2][32 * FS];
  __shared__ float S0[32 * 33];
  __shared__ float S1[2][32 * 17];
  const int flat = blockIdx.x;
  const int xcd = flat & 7;
  const int rr_ = flat >> 3;
  const int y = rr_ & 31;                 // 0..31
  const int n = (xcd << 2) | (rr_ >> 5);  // 0..31
  const int bb = n >> 3, q = n & 7;
  const int tid = threadIdx.x;
  const int lane = tid & 63;
  const int wave = __builtin_amdgcn_readfirstlane(tid >> 6);
  const int lr = lane & 15, kg = lane >> 4;
  const int xx = tid & 31;
  const int hi = tid >> 5;  // 0..7
  const float inv = 1.f / 160.f;
  const size_t obase = (size_t)(bb * 784 + q) * 1024 + (size_t)y * 32;

  // ---- stage f0 row: plain uint4 copies ----
#pragma unroll
  for (int i = 0; i < 5; ++i) {
    const int idx = tid + i * 256;  // < 1280
    const int plane = idx / 640, rem = idx % 640;
    const int px = rem / 20, c16 = rem % 20;
    const short* src = (plane ? f0bl : f0bh) + ((size_t)n * 1024 + y * 32 + px) * 160 + c16 * 8;
    *reinterpret_cast<uint4*>(&f0L[plane][px * FS + c16 * 8]) =
        *reinterpret_cast<const uint4*>(src);
  }
  __syncthreads();

  // ---- hoist A-fragments ----
  const int mi0 = wave >> 1, ni0 = wave & 1;
  short8 a0h[5], a0l[5];
#pragma unroll
  for (int ks = 0; ks < 5; ++ks) {
    a0h[ks] = *reinterpret_cast<const short8*>(&f0L[0][(mi0 * 16 + lr) * FS + ks * 32 + kg * 8]);
    a0l[ks] = *reinterpret_cast<const short8*>(&f0L[1][(mi0 * 16 + lr) * FS + ks * 32 + kg * 8]);
  }

  // ---- level 0 ----
  for (int dyi = 0; dyi < 7; ++dyi) {
    const int yy = y + dyi - 3;
    const bool inr = (unsigned)yy < 32u;
    __syncthreads();
    if (inr) {
#pragma unroll
      for (int i = 0; i < 5; ++i) {
        const int idx = tid + i * 256;
        const int plane = idx / 640, rem = idx % 640;
        const int px = rem / 20, c16 = rem % 20;
        const short* src = (plane ? f1bl : f1bh) + ((size_t)n * 1024 + yy * 32 + px) * 160 + c16 * 8;
        *reinterpret_cast<uint4*>(&f1L[plane][px * FS + c16 * 8]) =
            *reinterpret_cast<const uint4*>(src);
      }
    }
    __syncthreads();
    if (inr) {
      f32x4 aA = {0.f, 0.f, 0.f, 0.f}, aB = aA, aC = aA;
#pragma unroll
      for (int ks = 0; ks < 5; ++ks) {
        const short8 bh = *reinterpret_cast<const short8*>(&f1L[0][(ni0 * 16 + lr) * FS + ks * 32 + kg * 8]);
        const short8 bl = *reinterpret_cast<const short8*>(&f1L[1][(ni0 * 16 + lr) * FS + ks * 32 + kg * 8]);
        aA = __builtin_amdgcn_mfma_f32_16x16x32_bf16(a0h[ks], bh, aA, 0, 0, 0);
        aB = __builtin_amdgcn_mfma_f32_16x16x32_bf16(a0h[ks], bl, aB, 0, 0, 0);
        aC = __builtin_amdgcn_mfma_f32_16x16x32_bf16(a0l[ks], bh, aC, 0, 0, 0);
      }
#pragma unroll
      for (int r = 0; r < 4; ++r)
        S0[(mi0 * 16 + kg * 4 + r) * 33 + ni0 * 16 + lr] = (aA[r] + aB[r]) + aC[r];
    }
    __syncthreads();
    if (hi < 7) {
      const int x2 = xx + hi - 3;
      const float val = (inr && (unsigned)x2 < 32u) ? S0[xx * 33 + x2] * inv : 0.f;
      out[obase + (size_t)(hi * 7 + dyi) * 8192 + xx] = val;
    }
  }

  // ---- level 1: corner dots on pooled planes, rolling S1 + fused combine ----
  short8 a1h[5], a1l[5];
  if (wave < 2) {
#pragma unroll
    for (int ks = 0; ks < 5; ++ks) {
      a1h[ks] = *reinterpret_cast<const short8*>(&f0L[0][(wave * 16 + lr) * FS + ks * 32 + kg * 8]);
      a1l[ks] = *reinterpret_cast<const short8*>(&f0L[1][(wave * 16 + lr) * FS + ks * 32 + kg * 8]);
    }
  }
  const int Y0 = (y >> 1) - 3;
  const float wy = (y & 1) ? 0.5f : 0.f;
  for (int v = 0; v < 8; ++v) {
    const int Y = Y0 + v;
    const bool inr = (unsigned)Y < 16u;
    __syncthreads();
    if (inr) {
#pragma unroll
      for (int i = 0; i < 3; ++i) {
        const int idx = tid + i * 256;
        if (idx < 640) {
          const int plane = idx / 320, rem = idx % 320;
          const int px = rem / 20, c16 = rem % 20;
          const short* src = (plane ? g1pbl : g1pbh) + ((size_t)n * 256 + Y * 16 + px) * 160 + c16 * 8;
          *reinterpret_cast<uint4*>(&f1L[plane][px * FS + c16 * 8]) =
              *reinterpret_cast<const uint4*>(src);
        }
      }
    }
    __syncthreads();
    if (wave < 2) {
      f32x4 aA = {0.f, 0.f, 0.f, 0.f}, aB = aA, aC = aA;
      if (inr) {
#pragma unroll
        for (int ks = 0; ks < 5; ++ks) {
          const short8 bh = *reinterpret_cast<const short8*>(&f1L[0][lr * FS + ks * 32 + kg * 8]);
          const short8 bl = *reinterpret_cast<const short8*>(&f1L[1][lr * FS + ks * 32 + kg * 8]);
          aA = __builtin_amdgcn_mfma_f32_16x16x32_bf16(a1h[ks], bh, aA, 0, 0, 0);
          aB = __builtin_amdgcn_mfma_f32_16x16x32_bf16(a1h[ks], bl, aB, 0, 0, 0);
          aC = __builtin_amdgcn_mfma_f32_16x16x32_bf16(a1l[ks], bh, aC, 0, 0, 0);
        }
      }
#pragma unroll
      for (int r = 0; r < 4; ++r)
        S1[v & 1][(wave * 16 + kg * 4 + r) * 17 + lr] = (aA[r] + aB[r]) + aC[r];
    }
    __syncthreads();
    if (v >= 1 && hi < 7) {
      const int dyi = v - 1;
      const int Xl = (xx >> 1) - 3 + hi;
      const int Xr = Xl + 1;
      const float* t0 = S1[(v - 1) & 1];
      const float* t1 = S1[v & 1];
      const float a00 = ((unsigned)Xl < 16u) ? t0[xx * 17 + Xl] : 0.f;
      const float a01 = ((unsigned)Xr < 16u) ? t0[xx * 17 + Xr] : 0.f;
      const float a10 = ((unsigned)Xl < 16u) ? t1[xx * 17 + Xl] : 0.f;
      const float a11 = ((unsigned)Xr < 16u) ? t1[xx * 17 + Xr] : 0.f;
      const float wx = (xx & 1) ? 0.5f : 0.f;
      const float val = ((1.f - wx) * ((1.f - wy) * a00 + wy * a10) +
                         wx * ((1.f - wy) * a01 + wy * a11)) * inv;
      out[obase + (size_t)(49 + hi * 7 + dyi) * 8192 + xx] = val;
    }
  }
}

// ---------------------------------------------------------------------------
extern "C" void kernel_launch(void* const* d_in, const int* in_sizes, int n_in,
                              void* d_out, int out_size, void* d_ws,
                              size_t ws_size, hipStream_t stream) {
  const float* x = (const float*)d_in[0];
  const float* w0 = (const float*)d_in[1];
  const float* w1 = (const float*)d_in[2];
  short* f0bh = (short*)d_ws;
  short* f0bl = f0bh + PL;
  short* f1bh = f0bl + PL;
  short* f1bl = f1bh + PL;
  short* g1pbh = f1bl + PL;
  short* g1pbl = g1pbh + PPL;
  short* wprep = g1pbh;  // overlapped: consumed by conv before pool writes
  float* out = (float*)d_out;

  wprep_kernel<<<1000, 256, 0, stream>>>(w0, w1, wprep);
  conv_q<<<dim3(32, 8, 4), 256, 0, stream>>>(x, wprep, f0bh, f0bl, f1bh, f1bl);
  pool_b<<<640, 256, 0, stream>>>(f1bh, f1bl, g1pbh, g1pbl);
  corr_kernel<<<1024, 256, 0, stream>>>(f0bh, f0bl, f1bh, f1bl, g1pbh, g1pbl, out);
}

// Round 8
// 97.075 us; speedup vs baseline: 1.4238x; 1.4238x over previous
//
#include <hip/hip_runtime.h>
#include <hip/hip_bf16.h>

typedef __attribute__((ext_vector_type(8))) short short8;   // 8 bf16 (4 VGPRs)
typedef __attribute__((ext_vector_type(4))) float f32x4;    // MFMA acc

// Problem constants
static constexpr int HW = 1024;   // 32*32
static constexpr int C2 = 160;    // corr channel count
static constexpr int FS = 168;    // corr/epilogue LDS row stride in shorts (336 B)
static constexpr int XBS = 42;    // conv xB row stride in shorts: 21 dwords, odd ->
                                  // 32 px cover all 32 banks on b32 writes (was 40 -> 8-way)
static constexpr int WPLANE = 160 * 40;  // shorts per (ks,mat,hl) w-plane
static constexpr int WKS = 4 * WPLANE;
static constexpr int KSTEPS = 10;
static constexpr size_t PL = 32ull * 1024 * 160;   // shorts per f-plane (10.49MB)
static constexpr size_t PPL = 32ull * 256 * 160;   // shorts per pooled plane

__device__ inline short bfh(float v) {
  __hip_bfloat16 h = __float2bfloat16(v);
  return *reinterpret_cast<short*>(&h);
}
__device__ inline float bff(short s) {
  union { unsigned u; float f; } c;
  c.u = ((unsigned)(unsigned short)s) << 16;
  return c.f;
}
__device__ inline unsigned packhl(float v0, float v1, unsigned& lo) {
  const short h0 = bfh(v0), h1 = bfh(v1);
  const short l0 = bfh(v0 - bff(h0)), l1 = bfh(v1 - bff(h1));
  lo = (unsigned)(unsigned short)l0 | ((unsigned)(unsigned short)l1 << 16);
  return (unsigned)(unsigned short)h0 | ((unsigned)(unsigned short)h1 << 16);
}
// dword-aligned (not 16B-aligned) LDS short8 load as 4x b32
__device__ inline short8 ld8_b32(const short* p) {
  const unsigned* q = reinterpret_cast<const unsigned*>(p);
  union { unsigned u[4]; short8 s; } U;
  U.u[0] = q[0]; U.u[1] = q[1]; U.u[2] = q[2]; U.u[3] = q[3];
  return U.s;
}

// ---------------------------------------------------------------------------
// Kernel 0: pre-split w into bf16 (hi,lo) planes, tiled per k-step (unchanged).
// wp[ks][mat][hl][o 160][kk 40], kk 32..39 zero.
// ---------------------------------------------------------------------------
__global__ __launch_bounds__(256)
void wprep_kernel(const float* __restrict__ w0, const float* __restrict__ w1,
                  short* __restrict__ wp) {
  const int id = blockIdx.x * 256 + threadIdx.x;
  if (id >= KSTEPS * WKS) return;
  const int kk = id % 40;
  const int o = (id / 40) % 160;
  const int hl = (id / 6400) % 2;
  const int mat = (id / 12800) % 2;
  const int ks = id / 25600;
  short outv = 0;
  if (kk < 32) {
    const float v = (mat ? w1 : w0)[o * 320 + ks * 32 + kk];
    const short hb = bfh(v);
    outv = hl ? bfh(v - bff(hb)) : hb;
  }
  wp[id] = outv;
}

// ---------------------------------------------------------------------------
// Kernel 1: fused 1x1 convs producing the interleaved split-bf16 f-tensors
// (round-6 structure, verified). ROUND-8 CHANGE: xB stride 40 -> 42 shorts
// (odd dword stride kills the 8-way staging-write bank conflict); B-frags
// read via 4x b32 (84B rows are dword- but not 16B-aligned). All else
// byte-identical to round 6.
// ---------------------------------------------------------------------------
__global__ __launch_bounds__(256)
void conv_fused(const float* __restrict__ x, const short* __restrict__ wprep,
                short* __restrict__ f0bh, short* __restrict__ f0bl,
                short* __restrict__ f1bh, short* __restrict__ f1bl) {
  __shared__ __align__(16) short xB[2][288 * XBS];  // [hl][col=f*32+px][kk]
  __shared__ __align__(16) short aL[2][80 * 40];    // [hl][gr][kk]
  const int pxt = blockIdx.x;  // 0..31
  const int qp = blockIdx.y;   // 0..3
  const int bb = blockIdx.z;   // 0..3
  const int tid = threadIdx.x;
  const int lane = tid & 63;
  const int wave = __builtin_amdgcn_readfirstlane(tid >> 6);
  const int lr = lane & 15, kg = lane >> 4;
  const int pxh = wave & 1;   // px half (16)
  const int fpar = wave >> 1; // frame parity: f in {fpar, fpar+2, ...}

  f32x4 acc[5][5];
#pragma unroll
  for (int mt = 0; mt < 5; ++mt)
#pragma unroll
    for (int fi = 0; fi < 5; ++fi)
#pragma unroll
      for (int r = 0; r < 4; ++r) acc[mt][fi][r] = 0.f;

  const size_t xbase = (size_t)bb * 320 * 9216 + (size_t)pxt * 32;

  for (int ks = 0; ks < KSTEPS; ++ks) {
    __syncthreads();
    // stage A (w rows for this q-pair): 800 uint4 plain copies
#pragma unroll
    for (int i = 0; i < 4; ++i) {
      const int idx = tid + i * 256;
      if (idx < 800) {
        const int u = idx % 5, gr = (idx / 5) % 80, hl = idx / 400;
        const int mat = gr >= 40;
        const int o = qp * 40 + (gr - mat * 40);
        const uint4* s = reinterpret_cast<const uint4*>(
            wprep + (size_t)((ks * 2 + mat) * 2 + hl) * WPLANE + o * 40) + u;
        reinterpret_cast<uint4*>(&aL[hl][gr * 40])[u] = *s;
      }
    }
    // stage x (convert fp32 -> h/l bf16): 4608 c-pairs
#pragma unroll
    for (int i = 0; i < 18; ++i) {
      const int id = tid + i * 256;
      const int px = id & 31, f = (id >> 5) % 9, kl2 = id / 288;  // kl2 0..15
      const float* xp =
          x + xbase + (size_t)(ks * 32 + 2 * kl2) * 9216 + f * 1024 + px;
      const float v0 = xp[0], v1 = xp[9216];
      unsigned lo;
      const unsigned hp = packhl(v0, v1, lo);
      *reinterpret_cast<unsigned*>(&xB[0][(f * 32 + px) * XBS + 2 * kl2]) = hp;
      *reinterpret_cast<unsigned*>(&xB[1][(f * 32 + px) * XBS + 2 * kl2]) = lo;
    }
    __syncthreads();
    // MFMA: hold A-frags, loop frames
    short8 Ah[5], Al[5];
#pragma unroll
    for (int mt = 0; mt < 5; ++mt) {
      Ah[mt] = *reinterpret_cast<const short8*>(&aL[0][(mt * 16 + lr) * 40 + kg * 8]);
      Al[mt] = *reinterpret_cast<const short8*>(&aL[1][(mt * 16 + lr) * 40 + kg * 8]);
    }
#pragma unroll
    for (int fi = 0; fi < 5; ++fi) {
      if (2 * fi + fpar < 9) {
        const int f = 2 * fi + fpar;
        const int col = (f * 32 + pxh * 16 + lr) * XBS + kg * 8;
        const short8 Bh = ld8_b32(&xB[0][col]);
        const short8 Bl = ld8_b32(&xB[1][col]);
#pragma unroll
        for (int mt = 0; mt < 5; ++mt) {
          acc[mt][fi] = __builtin_amdgcn_mfma_f32_16x16x32_bf16(Ah[mt], Bh, acc[mt][fi], 0, 0, 0);
          acc[mt][fi] = __builtin_amdgcn_mfma_f32_16x16x32_bf16(Ah[mt], Bl, acc[mt][fi], 0, 0, 0);
          acc[mt][fi] = __builtin_amdgcn_mfma_f32_16x16x32_bf16(Al[mt], Bh, acc[mt][fi], 0, 0, 0);
        }
      }
    }
  }

  // ---- epilogue: two mat-passes through LDS transpose (tL overlays xB) ----
  short* tL = &xB[0][0];  // [2 planes][64 rows][168]
#pragma unroll
  for (int m = 0; m < 2; ++m) {
    __syncthreads();  // previous readers of xB/tL done
#pragma unroll
    for (int mt = 0; mt < 5; ++mt)
#pragma unroll
      for (int fi = 0; fi < 5; ++fi) {
        const int f = 2 * fi + fpar;
        const int tt = f - m;
        if (f < 9 && (unsigned)tt < 8u) {
#pragma unroll
          for (int rr = 0; rr < 4; ++rr) {
            const int gr = mt * 16 + kg * 4 + rr;
            if ((gr >= 40) == (m == 1)) {  // row belongs to this mat
              const int rowl = gr - m * 40;
              const int ql = rowl / 20, r20 = rowl % 20;
              const int c = 8 * r20 + tt;
              const int row = ql * 32 + pxh * 16 + lr;
              const float v = acc[mt][fi][rr];
              const short h = bfh(v);
              const short l = bfh(v - bff(h));
              tL[row * FS + c] = h;
              tL[10752 + row * FS + c] = l;
            }
          }
        }
      }
    __syncthreads();
    // coalesced copy-out: 2560 uint4
#pragma unroll
    for (int i = 0; i < 10; ++i) {
      const int idx = tid + i * 256;
      const int plane = idx / 1280, rem = idx % 1280;
      const int row = rem / 20, c16 = rem % 20;
      const int ql = row >> 5, pxl = row & 31;
      const int n = bb * 8 + qp * 2 + ql;
      short* dst = (m == 0) ? (plane ? f0bl : f0bh) : (plane ? f1bl : f1bh);
      *reinterpret_cast<uint4*>(dst + ((size_t)n * 1024 + pxt * 32 + pxl) * 160 + c16 * 8) =
          *reinterpret_cast<const uint4*>(&tL[plane * 10752 + row * FS + c16 * 8]);
    }
  }
}

// ---------------------------------------------------------------------------
// Kernel 2: 2x2 avg-pool on the bf16 h/l planes (unchanged from round 6)
// ---------------------------------------------------------------------------
__global__ __launch_bounds__(256)
void pool_b(const short* __restrict__ f1bh, const short* __restrict__ f1bl,
            short* __restrict__ g1pbh, short* __restrict__ g1pbl) {
  const int id = blockIdx.x * 256 + threadIdx.x;  // 32*256*20
  if (id >= 32 * 256 * 20) return;
  const int c16 = id % 20;
  const int PX = (id / 20) & 255;
  const int n = id / (20 * 256);
  const int Y = PX >> 4, X = PX & 15;
  const int r0 = Y * 64 + X * 2;
  const size_t base = ((size_t)n * 1024 + r0) * 160 + c16 * 8;
  const short8 h00 = *reinterpret_cast<const short8*>(f1bh + base);
  const short8 h01 = *reinterpret_cast<const short8*>(f1bh + base + 160);
  const short8 h10 = *reinterpret_cast<const short8*>(f1bh + base + 32 * 160);
  const short8 h11 = *reinterpret_cast<const short8*>(f1bh + base + 33 * 160);
  const short8 l00 = *reinterpret_cast<const short8*>(f1bl + base);
  const short8 l01 = *reinterpret_cast<const short8*>(f1bl + base + 160);
  const short8 l10 = *reinterpret_cast<const short8*>(f1bl + base + 32 * 160);
  const short8 l11 = *reinterpret_cast<const short8*>(f1bl + base + 33 * 160);
  short8 ho, lo;
#pragma unroll
  for (int j = 0; j < 8; ++j) {
    const float v = 0.25f * ((bff(h00[j]) + bff(l00[j])) + (bff(h01[j]) + bff(l01[j])) +
                             (bff(h10[j]) + bff(l10[j])) + (bff(h11[j]) + bff(l11[j])));
    const short h = bfh(v);
    ho[j] = h;
    lo[j] = bfh(v - bff(h));
  }
  const size_t ob = ((size_t)n * 256 + PX) * 160 + c16 * 8;
  *reinterpret_cast<short8*>(g1pbh + ob) = ho;
  *reinterpret_cast<short8*>(g1pbl + ob) = lo;
}

// ---------------------------------------------------------------------------
// Kernel 3: correlation + pyramid sampling via split-bf16 MFMA
// (unchanged from round 6 — verified; XCD swizzle kept)
// ---------------------------------------------------------------------------
__global__ __launch_bounds__(256)
void corr_kernel(const short* __restrict__ f0bh, const short* __restrict__ f0bl,
                 const short* __restrict__ f1bh, const short* __restrict__ f1bl,
                 const short* __restrict__ g1pbh, const short* __restrict__ g1pbl,
                 float* __restrict__ out) {
  __shared__ __align__(16) short f0L[2][32 * FS];
  __shared__ __align__(16) short f1L[2][32 * FS];
  __shared__ float S0[32 * 33];
  __shared__ float S1[2][32 * 17];
  const int flat = blockIdx.x;
  const int xcd = flat & 7;
  const int rr_ = flat >> 3;
  const int y = rr_ & 31;                 // 0..31
  const int n = (xcd << 2) | (rr_ >> 5);  // 0..31
  const int bb = n >> 3, q = n & 7;
  const int tid = threadIdx.x;
  const int lane = tid & 63;
  const int wave = __builtin_amdgcn_readfirstlane(tid >> 6);
  const int lr = lane & 15, kg = lane >> 4;
  const int xx = tid & 31;
  const int hi = tid >> 5;  // 0..7
  const float inv = 1.f / 160.f;
  const size_t obase = (size_t)(bb * 784 + q) * 1024 + (size_t)y * 32;

  // ---- stage f0 row: plain uint4 copies ----
#pragma unroll
  for (int i = 0; i < 5; ++i) {
    const int idx = tid + i * 256;  // < 1280
    const int plane = idx / 640, rem = idx % 640;
    const int px = rem / 20, c16 = rem % 20;
    const short* src = (plane ? f0bl : f0bh) + ((size_t)n * 1024 + y * 32 + px) * 160 + c16 * 8;
    *reinterpret_cast<uint4*>(&f0L[plane][px * FS + c16 * 8]) =
        *reinterpret_cast<const uint4*>(src);
  }
  __syncthreads();

  // ---- hoist A-fragments ----
  const int mi0 = wave >> 1, ni0 = wave & 1;
  short8 a0h[5], a0l[5];
#pragma unroll
  for (int ks = 0; ks < 5; ++ks) {
    a0h[ks] = *reinterpret_cast<const short8*>(&f0L[0][(mi0 * 16 + lr) * FS + ks * 32 + kg * 8]);
    a0l[ks] = *reinterpret_cast<const short8*>(&f0L[1][(mi0 * 16 + lr) * FS + ks * 32 + kg * 8]);
  }

  // ---- level 0 ----
  for (int dyi = 0; dyi < 7; ++dyi) {
    const int yy = y + dyi - 3;
    const bool inr = (unsigned)yy < 32u;
    __syncthreads();
    if (inr) {
#pragma unroll
      for (int i = 0; i < 5; ++i) {
        const int idx = tid + i * 256;
        const int plane = idx / 640, rem = idx % 640;
        const int px = rem / 20, c16 = rem % 20;
        const short* src = (plane ? f1bl : f1bh) + ((size_t)n * 1024 + yy * 32 + px) * 160 + c16 * 8;
        *reinterpret_cast<uint4*>(&f1L[plane][px * FS + c16 * 8]) =
            *reinterpret_cast<const uint4*>(src);
      }
    }
    __syncthreads();
    if (inr) {
      f32x4 aA = {0.f, 0.f, 0.f, 0.f}, aB = aA, aC = aA;
#pragma unroll
      for (int ks = 0; ks < 5; ++ks) {
        const short8 bh = *reinterpret_cast<const short8*>(&f1L[0][(ni0 * 16 + lr) * FS + ks * 32 + kg * 8]);
        const short8 bl = *reinterpret_cast<const short8*>(&f1L[1][(ni0 * 16 + lr) * FS + ks * 32 + kg * 8]);
        aA = __builtin_amdgcn_mfma_f32_16x16x32_bf16(a0h[ks], bh, aA, 0, 0, 0);
        aB = __builtin_amdgcn_mfma_f32_16x16x32_bf16(a0h[ks], bl, aB, 0, 0, 0);
        aC = __builtin_amdgcn_mfma_f32_16x16x32_bf16(a0l[ks], bh, aC, 0, 0, 0);
      }
#pragma unroll
      for (int r = 0; r < 4; ++r)
        S0[(mi0 * 16 + kg * 4 + r) * 33 + ni0 * 16 + lr] = (aA[r] + aB[r]) + aC[r];
    }
    __syncthreads();
    if (hi < 7) {
      const int x2 = xx + hi - 3;
      const float val = (inr && (unsigned)x2 < 32u) ? S0[xx * 33 + x2] * inv : 0.f;
      out[obase + (size_t)(hi * 7 + dyi) * 8192 + xx] = val;
    }
  }

  // ---- level 1: corner dots on pooled planes, rolling S1 + fused combine ----
  short8 a1h[5], a1l[5];
  if (wave < 2) {
#pragma unroll
    for (int ks = 0; ks < 5; ++ks) {
      a1h[ks] = *reinterpret_cast<const short8*>(&f0L[0][(wave * 16 + lr) * FS + ks * 32 + kg * 8]);
      a1l[ks] = *reinterpret_cast<const short8*>(&f0L[1][(wave * 16 + lr) * FS + ks * 32 + kg * 8]);
    }
  }
  const int Y0 = (y >> 1) - 3;
  const float wy = (y & 1) ? 0.5f : 0.f;
  for (int v = 0; v < 8; ++v) {
    const int Y = Y0 + v;
    const bool inr = (unsigned)Y < 16u;
    __syncthreads();
    if (inr) {
#pragma unroll
      for (int i = 0; i < 3; ++i) {
        const int idx = tid + i * 256;
        if (idx < 640) {
          const int plane = idx / 320, rem = idx % 320;
          const int px = rem / 20, c16 = rem % 20;
          const short* src = (plane ? g1pbl : g1pbh) + ((size_t)n * 256 + Y * 16 + px) * 160 + c16 * 8;
          *reinterpret_cast<uint4*>(&f1L[plane][px * FS + c16 * 8]) =
              *reinterpret_cast<const uint4*>(src);
        }
      }
    }
    __syncthreads();
    if (wave < 2) {
      f32x4 aA = {0.f, 0.f, 0.f, 0.f}, aB = aA, aC = aA;
      if (inr) {
#pragma unroll
        for (int ks = 0; ks < 5; ++ks) {
          const short8 bh = *reinterpret_cast<const short8*>(&f1L[0][lr * FS + ks * 32 + kg * 8]);
          const short8 bl = *reinterpret_cast<const short8*>(&f1L[1][lr * FS + ks * 32 + kg * 8]);
          aA = __builtin_amdgcn_mfma_f32_16x16x32_bf16(a1h[ks], bh, aA, 0, 0, 0);
          aB = __builtin_amdgcn_mfma_f32_16x16x32_bf16(a1h[ks], bl, aB, 0, 0, 0);
          aC = __builtin_amdgcn_mfma_f32_16x16x32_bf16(a1l[ks], bh, aC, 0, 0, 0);
        }
      }
#pragma unroll
      for (int r = 0; r < 4; ++r)
        S1[v & 1][(wave * 16 + kg * 4 + r) * 17 + lr] = (aA[r] + aB[r]) + aC[r];
    }
    __syncthreads();
    if (v >= 1 && hi < 7) {
      const int dyi = v - 1;
      const int Xl = (xx >> 1) - 3 + hi;
      const int Xr = Xl + 1;
      const float* t0 = S1[(v - 1) & 1];
      const float* t1 = S1[v & 1];
      const float a00 = ((unsigned)Xl < 16u) ? t0[xx * 17 + Xl] : 0.f;
      const float a01 = ((unsigned)Xr < 16u) ? t0[xx * 17 + Xr] : 0.f;
      const float a10 = ((unsigned)Xl < 16u) ? t1[xx * 17 + Xl] : 0.f;
      const float a11 = ((unsigned)Xr < 16u) ? t1[xx * 17 + Xr] : 0.f;
      const float wx = (xx & 1) ? 0.5f : 0.f;
      const float val = ((1.f - wx) * ((1.f - wy) * a00 + wy * a10) +
                         wx * ((1.f - wy) * a01 + wy * a11)) * inv;
      out[obase + (size_t)(49 + hi * 7 + dyi) * 8192 + xx] = val;
    }
  }
}

// ---------------------------------------------------------------------------
extern "C" void kernel_launch(void* const* d_in, const int* in_sizes, int n_in,
                              void* d_out, int out_size, void* d_ws,
                              size_t ws_size, hipStream_t stream) {
  const float* x = (const float*)d_in[0];
  const float* w0 = (const float*)d_in[1];
  const float* w1 = (const float*)d_in[2];
  short* f0bh = (short*)d_ws;
  short* f0bl = f0bh + PL;
  short* f1bh = f0bl + PL;
  short* f1bl = f1bh + PL;
  short* g1pbh = f1bl + PL;
  short* g1pbl = g1pbh + PPL;
  short* wprep = g1pbh;  // overlapped: consumed by conv before pool writes
  float* out = (float*)d_out;

  wprep_kernel<<<1000, 256, 0, stream>>>(w0, w1, wprep);
  conv_fused<<<dim3(32, 4, 4), 256, 0, stream>>>(x, wprep, f0bh, f0bl, f1bh, f1bl);
  pool_b<<<640, 256, 0, stream>>>(f1bh, f1bl, g1pbh, g1pbl);
  corr_kernel<<<1024, 256, 0, stream>>>(f0bh, f0bl, f1bh, f1bl, g1pbh, g1pbl, out);
}